// Round 22
// baseline (79.818 us; speedup 1.0000x reference)
//
#include <hip/hip_runtime.h>
#include <hip/hip_bf16.h>
#include <stdint.h>

#define I_DIM 2048
#define O_DIM 8192
#define T_TOK 512
#define NSTR  64
#define BK    64
#define NSTEP (I_DIM / BK)

#define TILE_B 16384  // bytes per (stripe,step): B-hi, FRAGMENT-MAJOR layout

// gemm18 LDS: A-hi dbuf 2 x 4KB = 8KB, thr 8KB @ 8192 -> 16KB
#define THR_S 8192
#define SMEM18 16384

// workspace layout
#define WT_OFF   ((size_t)0)             // 32MB weight hi-tiles (fragment-major)
#define XC_OFF   ((size_t)67108864)      // 4MB xc f32
#define THR_OFF  ((size_t)71303168)      // 512KB thrs f32[64][2048]
#define PM_OFF   ((size_t)71827456)      // 2MB pm_part f32[64][8192]
#define PMB_OFF  ((size_t)73924608)      // 32KB pmb f32[8192]
#define CNT_OFF  ((size_t)73957376)      // 2KB counts i32[512]

typedef __attribute__((ext_vector_type(8))) short bf16x8;
typedef __attribute__((ext_vector_type(4))) float f32x4;
typedef __attribute__((ext_vector_type(4))) int i32x4;

// k0: fused prep: xc = x - mu; thrs = thresholds*std; zero counts.
__global__ void cwic_prep(const float* __restrict__ x, const float* __restrict__ mu,
                          const float* __restrict__ thresholds,
                          const float* __restrict__ stdv, float* __restrict__ xc,
                          float* __restrict__ thrs, int* __restrict__ counts) {
  int idx = blockIdx.x * 256 + threadIdx.x;  // 262144 float4s of xc
  float4 xv = ((const float4*)x)[idx];
  float4 mv = ((const float4*)mu)[idx & 511];
  float4 r;
  r.x = xv.x - mv.x; r.y = xv.y - mv.y; r.z = xv.z - mv.z; r.w = xv.w - mv.w;
  ((float4*)xc)[idx] = r;
  if (idx < (NSTR * I_DIM) / 4) {  // 32768 float4s of thrs
    float4 t = ((const float4*)thresholds)[idx];
    float4 s = ((const float4*)stdv)[idx & 511];
    float4 ts;
    ts.x = t.x * s.x; ts.y = t.y * s.y; ts.z = t.z * s.z; ts.w = t.w * s.w;
    ((float4*)thrs)[idx] = ts;
  }
  if (idx < T_TOK) counts[idx] = 0;
}

// k1: wprep2 — LDS-transpose weight prep. Block = 32 w-rows (one kh-half) x
// 512 cols: reads 2KB contiguous bursts row-major into LDS, converts
// column-wise (8 rows -> one 16B fragment), writes fragment-major tiles +
// pm_part (row-sequential sum order == previous wprep, bit-identical).
__global__ __launch_bounds__(256) void cwic_wprep2(const float* __restrict__ w,
                                                   const float* __restrict__ mu,
                                                   char* __restrict__ wt,
                                                   float* __restrict__ pm_part) {
  const int bp = blockIdx.x;       // 1024 = 64 half-steps x 16 col-chunks
  const int hs = bp >> 4;          // rows hs*32 .. hs*32+31
  const int cc = bp & 15;          // cols cc*512 .. cc*512+511
  const int step = hs >> 1, kh = hs & 1;
  const int r0 = hs * 32;
  const int tid = threadIdx.x;
  __shared__ float ls[32][512];    // 64KB

  // stage: 16 passes x 2 rows, 128 float4/row (2KB contiguous per row segment)
  {
    const int sr = tid >> 7, sf = tid & 127;
    #pragma unroll 4
    for (int p = 0; p < 16; ++p) {
      const int row = p * 2 + sr;
      float4 v = *(const float4*)(w + (size_t)(r0 + row) * O_DIM + cc * 512 + sf * 4);
      *(float4*)&ls[row][sf * 4] = v;
    }
  }
  __syncthreads();

  float mus[32];
  #pragma unroll
  for (int r = 0; r < 32; ++r) mus[r] = mu[r0 + r];

  #pragma unroll
  for (int ci = 0; ci < 2; ++ci) {
    const int c = tid + ci * 256;          // col within chunk
    const int C = cc * 512 + c;            // global col
    const int n = C >> 7, o = C & 127;
    char* tb = wt + (size_t)(n * NSTEP + step) * TILE_B + (kh * 8 + (o >> 4)) * 1024;
    float pm = 0.0f;
    #pragma unroll
    for (int g = 0; g < 4; ++g) {
      unsigned hv[4];
      unsigned hprev = 0;
      #pragma unroll
      for (int e = 0; e < 8; ++e) {
        float v = ls[g * 8 + e][c];
        pm += mus[g * 8 + e] * v;
        unsigned u = __builtin_bit_cast(unsigned, v);
        unsigned r = u + 0x7fffu + ((u >> 16) & 1u);   // RNE to bf16
        unsigned short h = (unsigned short)(r >> 16);
        if ((e & 1) == 0) hprev = h;
        else hv[e >> 1] = hprev | (((unsigned)h) << 16);
      }
      *(i32x4*)(tb + ((o & 15) + g * 16) * 16) = *(i32x4*)hv;
    }
    pm_part[(size_t)(step * 2 + kh) * O_DIM + C] = pm;
  }
}

// k2: pmb[o] = bias[o] + sum_s pm_part[s][o] (fixed order, deterministic)
__global__ void cwic_pmb(const float* __restrict__ pm_part,
                         const float* __restrict__ bias, float* __restrict__ pmb) {
  int o = blockIdx.x * 256 + threadIdx.x;
  float s = bias[o];
  #pragma unroll 8
  for (int j = 0; j < 64; ++j) s += pm_part[(size_t)j * O_DIM + o];
  pmb[o] = s;
}

// k3: masked GEMM "B-direct, 1-product, token-split". Block = 32 tokens x 128
// cols, 4 waves (wave 16x64), grid 1024 = 4 blocks/CU (16KB LDS). A single RNE
// bf16 (R21-verified numerics); B frags global->reg; one __syncthreads/step.
__global__ __launch_bounds__(256, 4) void cwic_gemm18(
    const float* __restrict__ xc, const char* __restrict__ wt,
    const float* __restrict__ thrs, const float* __restrict__ pmb,
    float* __restrict__ y, int* __restrict__ counts) {
  extern __shared__ char smem[];
  const int b = blockIdx.x;
  // XCD swizzle: all 16 token-tiles of one stripe land on one XCD -> tiles L2-hot.
  const int nid = (b & 7) * 128 + (b >> 3);
  const int n = nid >> 4, th = nid & 15;
  const int trow0 = th * 32, ocol0 = n * 128;
  const int tid = threadIdx.x;
  const int lane = tid & 63, wid = tid >> 6;
  const int wr = wid >> 1, wc = wid & 1;
  const int l15 = lane & 15, l4 = lane >> 4;
  const int t_loc = tid >> 3, kq = tid & 7;  // A staging: token row (0..31), k-octet

  // ---- prologue: stage thr (8KB) into LDS ----
  float* thr_s = (float*)(smem + THR_S);
  {
    const float4* src = (const float4*)(thrs + (size_t)n * I_DIM);
    ((float4*)thr_s)[tid] = src[tid];
    ((float4*)thr_s)[tid + 256] = src[tid + 256];
  }
  __syncthreads();

  const float* xrow = xc + (size_t)(trow0 + t_loc) * I_DIM + kq * 8;
  const char* wfrag = wt + (size_t)(n * NSTEP) * TILE_B + (wc * 4) * 1024 + lane * 16;

  f32x4 acc[4];
  #pragma unroll
  for (int ni = 0; ni < 4; ++ni) acc[ni] = (f32x4)(0.0f);
  int cnt = 0;

  for (int step = 0; step < NSTEP; ++step) {
    const int abase = (step & 1) * 4096;  // A double-buffer (LDS addr)
    // (1) B fragments for THIS step -> regs (coalesced 1KB wave-loads, L2-hot)
    bf16x8 bfr[8];  // [s32*4 + ni], constant-indexed
    {
      const char* bp_ = wfrag + (size_t)step * TILE_B;
      #pragma unroll
      for (int f = 0; f < 8; ++f)
        bfr[f] = *(const bf16x8*)(bp_ + (((f >> 2) * 8) + (f & 3)) * 1024);
    }
    // (2) x for THIS step + thr from LDS (8 elems/thread)
    float4 xv0 = *(const float4*)(xrow + step * BK);
    float4 xv1 = *(const float4*)(xrow + step * BK + 4);
    float4 tv0 = *(const float4*)(thr_s + step * BK + kq * 8);
    float4 tv1 = *(const float4*)(thr_s + step * BK + kq * 8 + 4);
    // (3) A-build: mask+count + single RNE bf16 cast (R21-verified)
    {
      const float xs[8] = {xv0.x, xv0.y, xv0.z, xv0.w, xv1.x, xv1.y, xv1.z, xv1.w};
      const float ts[8] = {tv0.x, tv0.y, tv0.z, tv0.w, tv1.x, tv1.y, tv1.z, tv1.w};
      bf16x8 hv8;
      #pragma unroll
      for (int e = 0; e < 8; ++e) {
        const float xvv = xs[e], tvv = ts[e];
        bool keep = fabsf(xvv) > tvv;
        cnt += keep ? 1 : 0;
        float a = keep ? xvv : 0.0f;
        __hip_bfloat16 h = __float2bfloat16(a);
        hv8[e] = __builtin_bit_cast(short, h);
      }
      const int ad = t_loc * 128 + ((kq * 16) ^ ((t_loc & 7) << 4));
      *(bf16x8*)(smem + abase + ad) = hv8;
    }
    __syncthreads();  // A[abase] writes visible (proven schedule)
    // (4) MFMA: A from LDS, B from regs (1 product)
    __builtin_amdgcn_s_setprio(1);
    #pragma unroll
    for (int s32 = 0; s32 < 2; ++s32) {
      const int r = wr * 16 + l15;
      const int ada = r * 128 + (((s32 * 64) + l4 * 16) ^ ((r & 7) << 4));
      bf16x8 afh = *(const bf16x8*)(smem + abase + ada);
      #pragma unroll
      for (int ni = 0; ni < 4; ++ni) {
        acc[ni] = __builtin_amdgcn_mfma_f32_16x16x32_bf16(afh, bfr[s32 * 4 + ni], acc[ni], 0, 0, 0);
      }
    }
    __builtin_amdgcn_s_setprio(0);
    // no second barrier: next step writes the OTHER A buffer (dbuf WAR-safe)
  }

  // ---- mask-count reduce: 8 threads (kq) share one token row ----
  cnt += __shfl_xor(cnt, 1);
  cnt += __shfl_xor(cnt, 2);
  cnt += __shfl_xor(cnt, 4);
  if (kq == 0) atomicAdd(&counts[trow0 + t_loc], cnt);

  // ---- epilogue: y = acc + (post_mu + bias); C/D layout m89-verified ----
  #pragma unroll
  for (int ni = 0; ni < 4; ++ni) {
    const int o = ocol0 + wc * 64 + ni * 16 + l15;
    const float pv = pmb[o];
    const int row0 = trow0 + wr * 16 + l4 * 4;
    #pragma unroll
    for (int r = 0; r < 4; ++r) {
      y[(size_t)(row0 + r) * O_DIM + o] = acc[ni][r] + pv;
    }
  }
}

// k4: flops outputs. flops_sparse = 16777216 * cnt/(64*2048) = 128*cnt (exact).
__global__ void cwic_fin(const int* __restrict__ counts, float* __restrict__ outF) {
  int t = blockIdx.x * 256 + threadIdx.x;
  outF[t] = 16777216.0f;
  outF[T_TOK + t] = 128.0f * (float)counts[t];
}

extern "C" void kernel_launch(void* const* d_in, const int* in_sizes, int n_in,
                              void* d_out, int out_size, void* d_ws, size_t ws_size,
                              hipStream_t stream) {
  const float* x = (const float*)d_in[0];
  const float* w = (const float*)d_in[1];
  const float* bias = (const float*)d_in[2];
  const float* thresholds = (const float*)d_in[3];
  const float* mu = (const float*)d_in[4];
  const float* stdv = (const float*)d_in[5];
  float* y = (float*)d_out;

  char* ws = (char*)d_ws;
  char* wt = ws + WT_OFF;
  float* xc = (float*)(ws + XC_OFF);
  float* thrs = (float*)(ws + THR_OFF);
  float* pm_part = (float*)(ws + PM_OFF);
  float* pmb = (float*)(ws + PMB_OFF);
  int* counts = (int*)(ws + CNT_OFF);

  cwic_prep<<<1024, 256, 0, stream>>>(x, mu, thresholds, stdv, xc, thrs, counts);
  cwic_wprep2<<<1024, 256, 0, stream>>>(w, mu, wt, pm_part);
  cwic_pmb<<<32, 256, 0, stream>>>(pm_part, bias, pmb);
  cwic_gemm18<<<1024, 256, SMEM18, stream>>>(xc, wt, thrs, pmb, y, counts);
  cwic_fin<<<2, 256, 0, stream>>>(counts, y + (size_t)T_TOK * O_DIM);
}